// Round 7
// baseline (159.775 us; speedup 1.0000x reference)
//
#include <hip/hip_runtime.h>
#include <hip/hip_bf16.h>

typedef __bf16   bf16x8 __attribute__((ext_vector_type(8)));
typedef _Float16 f16x8  __attribute__((ext_vector_type(8)));
typedef _Float16 f16x4  __attribute__((ext_vector_type(4)));
typedef float    f32x4  __attribute__((ext_vector_type(4)));

#define NTOK 4096
#define CDIM 512
#define HEADS 8
#define HD 64

__device__ __forceinline__ void gload_lds16(const void* g, void* l) {
    __builtin_amdgcn_global_load_lds((const __attribute__((address_space(1))) void*)g,
                                     (__attribute__((address_space(3))) void*)l, 16, 0, 0);
}

// ---------------------------------------------------------------------------
// P1 (merged): blocks x<64: x [sb][n][c] f32 -> XT [sb][kb][c][kk] fp16.
//              blocks x>=64: Wv transpose -> wvt fp16 [s][j][k].
// ---------------------------------------------------------------------------
__global__ __launch_bounds__(256, 3) void xpose_kernel(const float* __restrict__ x1,
                                                       const float* __restrict__ x2,
                                                       const float* __restrict__ Wkv1,
                                                       const float* __restrict__ Wkv2,
                                                       _Float16* __restrict__ xt,
                                                       _Float16* __restrict__ wvt) {
    const int t = threadIdx.x, w = t >> 6, l = t & 63;

    if (blockIdx.x >= 64) {
        // ---- wtrans role ----
        if (blockIdx.z >= 8) return;
        const int s = blockIdx.x - 64;
        const float* W = (s ? Wkv2 : Wkv1);
        const int k0 = blockIdx.z * 64;
        const int j = blockIdx.y * 256 + w * 64 + l;

        f16x8 vh[8];
        #pragma unroll
        for (int q = 0; q < 64; ++q) {
            float v = W[(size_t)(k0 + q) * (2 * CDIM) + CDIM + j];
            vh[q >> 3][q & 7] = (_Float16)v;
        }
        _Float16* dh = wvt + ((size_t)s * CDIM + j) * CDIM + k0;
        #pragma unroll
        for (int q = 0; q < 8; ++q)
            *(f16x8*)&dh[q * 8] = vh[q];
        return;
    }

    // ---- xpose role ----
    const int kb = blockIdx.x, cb = blockIdx.y, sb = blockIdx.z;
    const int s = sb >> 3, b = sb & 7;
    const float* xs = (s ? x2 : x1) + (size_t)b * NTOK * CDIM
                    + (size_t)kb * 64 * CDIM + cb * 256;

    __shared__ _Float16 lds[64 * 256];

    // Phase A: all 16 loads issued before any LDS write (keep MLP high).
    float4 v[16];
    #pragma unroll
    for (int i = 0; i < 16; ++i) {
        const int n = 4 * i + w;
        v[i] = *(const float4*)&xs[(size_t)n * CDIM + l * 4];
    }
    #pragma unroll
    for (int i = 0; i < 16; ++i) {
        const int n = 4 * i + w;
        f16x4 p = {(_Float16)v[i].x, (_Float16)v[i].y, (_Float16)v[i].z, (_Float16)v[i].w};
        *(f16x4*)&lds[n * 256 + ((l ^ (n >> 3)) << 2)] = p;
    }
    __syncthreads();

    // Phase B: per q-instr the wave's 64 stores are byte-contiguous (1 KiB).
    const int kk8 = (l & 7);
    _Float16* dst = xt + ((size_t)(sb * 64 + kb) * CDIM + cb * 256) * 64;
    #pragma unroll
    for (int q = 0; q < 8; ++q) {
        const int cw = 64 * w + 8 * q + (l >> 3);
        const int c4s = (cw >> 2) ^ kk8, c2 = cw & 3;
        const int base = (c4s << 2) + c2 + kk8 * 8 * 256;
        f16x8 o;
        #pragma unroll
        for (int j = 0; j < 8; ++j)
            o[j] = lds[base + j * 256];
        *(f16x8*)&dst[(size_t)cw * 64 + kk8 * 8] = o;
    }
}

// ---------------------------------------------------------------------------
// Gram v3: GPh[split(4)][sb] = xt(k-quarter)^T xt(k-quarter), fp16 MFMA.
// BK=32, 1024 blocks = 4 blocks/CU (16 waves/CU cross-block overlap),
// 32 KiB LDS double-buffered, counted vmcnt(4), setprio on MFMA.
// Swizzle: chunk perm = lk ^ ((col ^ col>>2) & 3)  (<=2 lanes/bank-span).
// ---------------------------------------------------------------------------
__global__ __launch_bounds__(256, 4) void gram_kernel(const _Float16* __restrict__ xt,
                                                      _Float16* __restrict__ GPh) {
    const int id = blockIdx.x;                   // 1024
    const int vid = (id & 7) * 128 + (id >> 3);  // XCD-contiguous, bijective
    const int sb = vid >> 6, rest = vid & 63;
    const int split = rest >> 4, tile = rest & 15;
    const int I0 = (tile >> 2) * 128, J0 = (tile & 3) * 128;
    const _Float16* xb = xt + (size_t)sb * CDIM * NTOK;

    __shared__ _Float16 Ih[2][128 * 32];
    __shared__ _Float16 Jh[2][128 * 32];

    const int t = threadIdx.x, w = t >> 6, l = t & 63;
    const int wm = w >> 1, wn = w & 1, l15 = l & 15, lk = l >> 4;
    const int scol = w * 16 + (l >> 2), spos = l & 3;

    f32x4 acc[4][4];
    #pragma unroll
    for (int f = 0; f < 4; ++f)
        #pragma unroll
        for (int g = 0; g < 4; ++g) acc[f][g] = (f32x4)(0.0f);

    auto STAGE = [&](int bufi, int it) {
        const int kglob = split * 1024 + it * 32;
        const int kbi = kglob >> 6, khalf = (kglob >> 5) & 1;
        const _Float16* kbase = xb + (size_t)kbi * (CDIM * 64) + khalf * 32;
        #pragma unroll
        for (int r = 0; r < 2; ++r) {
            const int col = r * 64 + scol;
            const int kk0 = (spos ^ ((col ^ (col >> 2)) & 3)) * 8;
            gload_lds16(kbase + (size_t)(I0 + col) * 64 + kk0,
                        &Ih[bufi][(r * 256 + w * 64) * 8]);
            gload_lds16(kbase + (size_t)(J0 + col) * 64 + kk0,
                        &Jh[bufi][(r * 256 + w * 64) * 8]);
        }
    };

    STAGE(0, 0);
    for (int it = 0; it < 32; ++it) {
        const int cur = it & 1;
        if (it < 31) {
            STAGE(cur ^ 1, it + 1);
            asm volatile("s_waitcnt vmcnt(4)" ::: "memory");
        } else {
            asm volatile("s_waitcnt vmcnt(0)" ::: "memory");
        }
        __builtin_amdgcn_s_barrier();

        const _Float16* Ib = &Ih[cur][0];
        const _Float16* Jb = &Jh[cur][0];
        __builtin_amdgcn_s_setprio(1);
        {
            f16x8 a[4], bb[4];
            #pragma unroll
            for (int f = 0; f < 4; ++f) {
                const int i = wm * 64 + f * 16 + l15;
                a[f] = *(const f16x8*)&Ib[i * 32 + ((lk ^ ((i ^ (i >> 2)) & 3)) << 3)];
            }
            #pragma unroll
            for (int g = 0; g < 4; ++g) {
                const int j = wn * 64 + g * 16 + l15;
                bb[g] = *(const f16x8*)&Jb[j * 32 + ((lk ^ ((j ^ (j >> 2)) & 3)) << 3)];
            }
            #pragma unroll
            for (int f = 0; f < 4; ++f)
                #pragma unroll
                for (int g = 0; g < 4; ++g)
                    acc[f][g] = __builtin_amdgcn_mfma_f32_16x16x32_f16(a[f], bb[g], acc[f][g], 0, 0, 0);
        }
        __builtin_amdgcn_s_setprio(0);
        __builtin_amdgcn_s_barrier();
    }

    _Float16* Gout = GPh + ((size_t)split * 16 + sb) * CDIM * CDIM;
    #pragma unroll
    for (int f = 0; f < 4; ++f)
        #pragma unroll
        for (int g = 0; g < 4; ++g) {
            const int row0 = I0 + wm * 64 + f * 16 + lk * 4;
            const int col  = J0 + wn * 64 + g * 16 + l15;
            #pragma unroll
            for (int r = 0; r < 4; ++r)
                Gout[(size_t)(row0 + r) * CDIM + col] = (_Float16)acc[f][g][r];
        }
}

// ---------------------------------------------------------------------------
// T-partials: TP[ks2][sb] = (G0+G1+G2+G3)(k-range) @ Wv, single fp16 MFMA.
// 512 blocks (2/CU). A: 4x b128 fp16 + packed adds -> LDS. B: gload_lds.
// ---------------------------------------------------------------------------
__global__ __launch_bounds__(256) void t_kernel(const _Float16* __restrict__ GPh,
                                                const _Float16* __restrict__ wvt,
                                                _Float16* __restrict__ TP) {
    const int id = blockIdx.x;                  // 512
    const int vid = (id & 7) * 64 + (id >> 3);
    const int sb = vid >> 5, rest = vid & 31;
    const int ks2 = rest >> 4, tile = rest & 15;
    const int s = sb >> 3;
    const int I0 = (tile >> 2) * 128, J0 = (tile & 3) * 128;
    const _Float16* G0 = GPh + (size_t)sb * CDIM * CDIM;
    const _Float16* G1 = GPh + ((size_t)16 + sb) * CDIM * CDIM;
    const _Float16* G2 = GPh + ((size_t)32 + sb) * CDIM * CDIM;
    const _Float16* G3 = GPh + ((size_t)48 + sb) * CDIM * CDIM;
    const _Float16* Bv = wvt + (size_t)s * CDIM * CDIM;

    __shared__ _Float16 Ah[128 * 64];
    __shared__ _Float16 Jh[128 * 64];

    const int t = threadIdx.x, w = t >> 6, l = t & 63;
    const int wm = w >> 1, wn = w & 1, l15 = l & 15, lk = l >> 4;
    const int colr = w * 8 + (l >> 3), pos = l & 7;

    f32x4 acc[4][4];
    #pragma unroll
    for (int f = 0; f < 4; ++f)
        #pragma unroll
        for (int g = 0; g < 4; ++g) acc[f][g] = (f32x4)(0.0f);

    for (int it = 0; it < 4; ++it) {
        const int k0 = ks2 * 256 + it * 64;
        __syncthreads();
        // B stage first: async gloads fly while A-stage does its work
        #pragma unroll
        for (int r = 0; r < 4; ++r) {
            const int col = r * 32 + colr;
            const int swz = ((pos ^ (col & 7)) << 3);
            gload_lds16(Bv + (size_t)(J0 + col) * CDIM + k0 + swz, &Jh[r * 2048 + w * 512]);
        }
        // A stage: sum the four fp16 Gram partials, store swizzled
        #pragma unroll
        for (int r = 0; r < 4; ++r) {
            const int i = r * 32 + (t >> 3), ch = t & 7;
            const size_t off = (size_t)(I0 + i) * CDIM + k0 + ch * 8;
            f16x8 a0 = *(const f16x8*)&G0[off];
            f16x8 a1 = *(const f16x8*)&G1[off];
            f16x8 a2 = *(const f16x8*)&G2[off];
            f16x8 a3 = *(const f16x8*)&G3[off];
            f16x8 sum = (a0 + a1) + (a2 + a3);
            *(f16x8*)&Ah[i * 64 + ((ch ^ (i & 7)) << 3)] = sum;
        }
        __syncthreads();
        __builtin_amdgcn_s_setprio(1);
        #pragma unroll
        for (int ks = 0; ks < 2; ++ks) {
            f16x8 a[4], bb[4];
            #pragma unroll
            for (int f = 0; f < 4; ++f) {
                const int i = wm * 64 + f * 16 + l15;
                a[f] = *(const f16x8*)&Ah[i * 64 + ((ks * 4 + lk) ^ (i & 7)) * 8];
            }
            #pragma unroll
            for (int g = 0; g < 4; ++g) {
                const int j = wn * 64 + g * 16 + l15;
                bb[g] = *(const f16x8*)&Jh[j * 64 + ((ks * 4 + lk) ^ (j & 7)) * 8];
            }
            #pragma unroll
            for (int f = 0; f < 4; ++f)
                #pragma unroll
                for (int g = 0; g < 4; ++g)
                    acc[f][g] = __builtin_amdgcn_mfma_f32_16x16x32_f16(a[f], bb[g], acc[f][g], 0, 0, 0);
        }
        __builtin_amdgcn_s_setprio(0);
    }

    _Float16* Tb = TP + ((size_t)ks2 * 16 + sb) * CDIM * CDIM;
    #pragma unroll
    for (int f = 0; f < 4; ++f)
        #pragma unroll
        for (int g = 0; g < 4; ++g) {
            const int row0 = I0 + wm * 64 + f * 16 + lk * 4;
            const int col  = J0 + wn * 64 + g * 16 + l15;
            #pragma unroll
            for (int r = 0; r < 4; ++r)
                Tb[(size_t)(row0 + r) * CDIM + col] = (_Float16)acc[f][g][r];
        }
}

// ---------------------------------------------------------------------------
// ctx GEMM, K-split by 4: CP[kq][sb][h] = partial Wk_h^T (TP0+TP1)_h
// ---------------------------------------------------------------------------
__global__ __launch_bounds__(256) void ctx_gemm_kernel(const _Float16* __restrict__ TP,
                                                       const float* __restrict__ Wkv1,
                                                       const float* __restrict__ Wkv2,
                                                       float* __restrict__ CP) {
    const int h = blockIdx.x, sb = blockIdx.y, kq = blockIdx.z;
    const int s = sb >> 3;
    const float* W  = (s == 0 ? Wkv1 : Wkv2);
    const _Float16* T0 = TP + (size_t)sb * CDIM * CDIM;
    const _Float16* T1 = TP + ((size_t)16 + sb) * CDIM * CDIM;

    __shared__ float Kt[64][65];
    __shared__ float Tt[64][65];

    const int t = threadIdx.x;
    const int td = t >> 4, te = t & 15;
    float acc[4][4] = {};

    for (int it = 0; it < 2; ++it) {
        const int kc = kq * 128 + it * 64;
        __syncthreads();
        for (int i = 0; i < 16; ++i) {
            const int idx = t + i * 256;
            const int r = idx >> 6, cc = idx & 63;
            Kt[r][cc] = W[(size_t)(kc + r) * (2 * CDIM) + h * HD + cc];
            Tt[r][cc] = (float)T0[(size_t)(kc + r) * CDIM + h * HD + cc]
                      + (float)T1[(size_t)(kc + r) * CDIM + h * HD + cc];
        }
        __syncthreads();
        for (int k = 0; k < 64; ++k) {
            float a[4], bb[4];
            #pragma unroll
            for (int i = 0; i < 4; ++i) a[i] = Kt[k][td * 4 + i];
            #pragma unroll
            for (int j = 0; j < 4; ++j) bb[j] = Tt[k][te * 4 + j];
            #pragma unroll
            for (int i = 0; i < 4; ++i)
                #pragma unroll
                for (int j = 0; j < 4; ++j) acc[i][j] += a[i] * bb[j];
        }
    }
    float* out = CP + (size_t)(((kq * 16 + sb) * HEADS) + h) * HD * HD;
    for (int i = 0; i < 4; ++i)
        for (int j = 0; j < 4; ++j)
            out[(size_t)(td * 4 + i) * HD + te * 4 + j] = acc[i][j];
}

// ---------------------------------------------------------------------------
// ctx finish: sum 4 partials, scale, softmax over d -> smT fp16 [sb][h][e][d]
// ---------------------------------------------------------------------------
__global__ __launch_bounds__(256) void ctx_fin_kernel(const float* __restrict__ CP,
                                                      _Float16* __restrict__ smT) {
    const int h = blockIdx.x, sb = blockIdx.y;

    __shared__ float ctxs[64][65];
    __shared__ float mred[64], sred[64];

    const int t = threadIdx.x;
    const float scale = 0.125f;
    #pragma unroll
    for (int i = 0; i < 4; ++i) {
        const int idx4 = t + i * 256;            // float4 index
        const int d = idx4 >> 4, e4 = idx4 & 15;
        f32x4 sum = (f32x4)(0.0f);
        #pragma unroll
        for (int kq = 0; kq < 4; ++kq) {
            const float* p = CP + (size_t)(((kq * 16 + sb) * HEADS) + h) * HD * HD;
            f32x4 v = *(const f32x4*)&p[d * HD + e4 * 4];
            sum += v;
        }
        *(f32x4*)&ctxs[d][e4 * 4] = sum * scale;
    }
    __syncthreads();
    if (t < 64) {
        float m = -1e30f;
        for (int d = 0; d < 64; ++d) m = fmaxf(m, ctxs[d][t]);
        float ssum = 0.f;
        for (int d = 0; d < 64; ++d) ssum += expf(ctxs[d][t] - m);
        mred[t] = m;
        sred[t] = 1.0f / ssum;
    }
    __syncthreads();
    _Float16* smout = smT + (size_t)(sb * HEADS + h) * HD * HD;   // [e][d]
    #pragma unroll
    for (int i = 0; i < 16; ++i) {
        const int idx = t + i * 256;
        const int e = idx >> 6, d = idx & 63;
        smout[e * HD + d] = (_Float16)(expf(ctxs[d][e] - mred[e]) * sred[e]);
    }
}

// ---------------------------------------------------------------------------
// out: out_s[n, h*64+e] = sum_d x_s[n, h*64+d] * sm[1-s][h][d][e], fp16 MFMA
// ---------------------------------------------------------------------------
__global__ __launch_bounds__(256) void out_kernel(const float* __restrict__ x1,
                                                  const float* __restrict__ x2,
                                                  const _Float16* __restrict__ smT,
                                                  float* __restrict__ out) {
    const int id = blockIdx.x;                   // 4096
    const int vid = (id & 7) * 512 + (id >> 3);  // h-groups co-XCD
    const int h = vid & 7, nt = (vid >> 3) & 31, sb = vid >> 8;
    const int s = sb >> 3, b = sb & 7;
    const float* xs = (s ? x2 : x1) + (size_t)b * NTOK * CDIM;
    const _Float16* sm = smT + (size_t)((((1 - s) * 8 + b) * HEADS) + h) * HD * HD;
    const int n0 = nt * 128;

    __shared__ _Float16 Axt[128 * 64];   // [n][d] swizzled
    __shared__ _Float16 Bsm[64 * 64];    // [e][d] swizzled

    const int t = threadIdx.x, w = t >> 6, l = t & 63;
    const int l15 = l & 15, lk = l >> 4;

    // B stage via gl_lds (2 rounds)
    #pragma unroll
    for (int r = 0; r < 2; ++r) {
        const int e = r * 32 + w * 8 + (l >> 3), pos = l & 7;
        gload_lds16(sm + (size_t)e * HD + ((pos ^ (e & 7)) << 3), &Bsm[r * 2048 + w * 512]);
    }
    // A stage: x f32 -> fp16, swizzled ds_write_b64
    #pragma unroll
    for (int p = 0; p < 8; ++p) {
        const int row = p * 16 + (t >> 4), f4c = t & 15;
        float4 u = *(const float4*)&xs[(size_t)(n0 + row) * CDIM + h * HD + f4c * 4];
        f16x4 q = {(_Float16)u.x, (_Float16)u.y, (_Float16)u.z, (_Float16)u.w};
        const int byte = row * 128 + (((f4c >> 1) ^ (row & 7)) << 4) + ((f4c & 1) << 3);
        *(f16x4*)((char*)Axt + byte) = q;
    }
    __syncthreads();

    f32x4 acc[2][4];
    #pragma unroll
    for (int m = 0; m < 2; ++m)
        #pragma unroll
        for (int g = 0; g < 4; ++g) acc[m][g] = (f32x4)(0.0f);

    #pragma unroll
    for (int ks = 0; ks < 2; ++ks) {
        f16x8 a[2], bb[4];
        #pragma unroll
        for (int m = 0; m < 2; ++m) {
            const int row = w * 32 + m * 16 + l15;
            a[m] = *(const f16x8*)((char*)Axt + row * 128 + (((ks * 4 + lk) ^ (row & 7)) << 4));
        }
        #pragma unroll
        for (int g = 0; g < 4; ++g) {
            const int e = g * 16 + l15;
            bb[g] = *(const f16x8*)((char*)Bsm + e * 128 + (((ks * 4 + lk) ^ (e & 7)) << 4));
        }
        #pragma unroll
        for (int m = 0; m < 2; ++m)
            #pragma unroll
            for (int g = 0; g < 4; ++g)
                acc[m][g] = __builtin_amdgcn_mfma_f32_16x16x32_f16(a[m], bb[g], acc[m][g], 0, 0, 0);
    }

    float* ob = out + (size_t)s * (8ULL * NTOK * CDIM) + (size_t)b * NTOK * CDIM;
    #pragma unroll
    for (int m = 0; m < 2; ++m)
        #pragma unroll
        for (int g = 0; g < 4; ++g) {
            const int row0 = n0 + w * 32 + m * 16 + lk * 4;
            const int col  = h * HD + g * 16 + l15;
            #pragma unroll
            for (int r = 0; r < 4; ++r)
                ob[(size_t)(row0 + r) * CDIM + col] = acc[m][g][r];
        }
}

// ---------------------------------------------------------------------------
extern "C" void kernel_launch(void* const* d_in, const int* in_sizes, int n_in,
                              void* d_out, int out_size, void* d_ws, size_t ws_size,
                              hipStream_t stream) {
    const float* x1   = (const float*)d_in[0];
    const float* x2   = (const float*)d_in[1];
    const float* Wkv1 = (const float*)d_in[2];
    const float* Wkv2 = (const float*)d_in[3];
    float* out = (float*)d_out;

    // Scratch layout inside d_out (128 MiB); every region is dead before
    // out_kernel overwrites d_out. smT (1 MiB) lives in d_ws.
    char* base = (char*)d_out;
    _Float16* XT   = (_Float16*)(base + 0);            // 64 MiB [sb][kb][c][64]
    _Float16* WVT  = (_Float16*)(base + 67108864);     // 1 MiB fp16 [s][j][k]
    _Float16* GPh  = (_Float16*)(base + 68157440);     // 32 MiB fp16 (4 partials)
    _Float16* TP   = (_Float16*)(base + 101711872);    // 16 MiB fp16 (2 partials)
    float*    CP   = (float*)(base + 118489088);       // 8 MiB f32 (4 partials)
    _Float16* SMT  = (_Float16*)d_ws;                  // 1 MiB

    hipLaunchKernelGGL(xpose_kernel, dim3(66, 2, 16), dim3(256), 0, stream,
                       x1, x2, Wkv1, Wkv2, XT, WVT);
    hipLaunchKernelGGL(gram_kernel, dim3(1024), dim3(256), 0, stream, XT, GPh);
    hipLaunchKernelGGL(t_kernel, dim3(512), dim3(256), 0, stream, GPh, WVT, TP);
    hipLaunchKernelGGL(ctx_gemm_kernel, dim3(8, 16, 4), dim3(256), 0, stream,
                       TP, Wkv1, Wkv2, CP);
    hipLaunchKernelGGL(ctx_fin_kernel, dim3(8, 16), dim3(256), 0, stream, CP, SMT);
    hipLaunchKernelGGL(out_kernel, dim3(4096), dim3(256), 0, stream, x1, x2, SMT, out);
}

// Round 8
// 151.665 us; speedup vs baseline: 1.0535x; 1.0535x over previous
//
#include <hip/hip_runtime.h>
#include <hip/hip_bf16.h>

typedef __bf16   bf16x8 __attribute__((ext_vector_type(8)));
typedef _Float16 f16x8  __attribute__((ext_vector_type(8)));
typedef _Float16 f16x4  __attribute__((ext_vector_type(4)));
typedef float    f32x4  __attribute__((ext_vector_type(4)));

#define NTOK 4096
#define CDIM 512
#define HEADS 8
#define HD 64

__device__ __forceinline__ void gload_lds16(const void* g, void* l) {
    __builtin_amdgcn_global_load_lds((const __attribute__((address_space(1))) void*)g,
                                     (__attribute__((address_space(3))) void*)l, 16, 0, 0);
}

// ---------------------------------------------------------------------------
// P1 (merged): blocks x<64: x [sb][n][c] f32 -> XT [sb][kb][c][kk] fp16.
//              blocks x>=64: Wv transpose -> wvt fp16 [s][j][k].
// ---------------------------------------------------------------------------
__global__ __launch_bounds__(256, 4) void xpose_kernel(const float* __restrict__ x1,
                                                       const float* __restrict__ x2,
                                                       const float* __restrict__ Wkv1,
                                                       const float* __restrict__ Wkv2,
                                                       _Float16* __restrict__ xt,
                                                       _Float16* __restrict__ wvt) {
    const int t = threadIdx.x, w = t >> 6, l = t & 63;

    if (blockIdx.x >= 64) {
        // ---- wtrans role ----
        if (blockIdx.z >= 8) return;
        const int s = blockIdx.x - 64;
        const float* W = (s ? Wkv2 : Wkv1);
        const int k0 = blockIdx.z * 64;
        const int j = blockIdx.y * 256 + w * 64 + l;

        f16x8 vh[8];
        #pragma unroll
        for (int q = 0; q < 64; ++q) {
            float v = W[(size_t)(k0 + q) * (2 * CDIM) + CDIM + j];
            vh[q >> 3][q & 7] = (_Float16)v;
        }
        _Float16* dh = wvt + ((size_t)s * CDIM + j) * CDIM + k0;
        #pragma unroll
        for (int q = 0; q < 8; ++q)
            *(f16x8*)&dh[q * 8] = vh[q];
        return;
    }

    // ---- xpose role ----
    const int kb = blockIdx.x, cb = blockIdx.y, sb = blockIdx.z;
    const int s = sb >> 3, b = sb & 7;
    const float* xs = (s ? x2 : x1) + (size_t)b * NTOK * CDIM
                    + (size_t)kb * 64 * CDIM + cb * 256;

    __shared__ _Float16 lds[64 * 256];

    // Phase A: all 16 loads issued before any LDS write (keep MLP high).
    float4 v[16];
    #pragma unroll
    for (int i = 0; i < 16; ++i) {
        const int n = 4 * i + w;
        v[i] = *(const float4*)&xs[(size_t)n * CDIM + l * 4];
    }
    #pragma unroll
    for (int i = 0; i < 16; ++i) {
        const int n = 4 * i + w;
        f16x4 p = {(_Float16)v[i].x, (_Float16)v[i].y, (_Float16)v[i].z, (_Float16)v[i].w};
        *(f16x4*)&lds[n * 256 + ((l ^ (n >> 3)) << 2)] = p;
    }
    __syncthreads();

    // Phase B: per q-instr the wave's 64 stores are byte-contiguous (1 KiB).
    const int kk8 = (l & 7);
    _Float16* dst = xt + ((size_t)(sb * 64 + kb) * CDIM + cb * 256) * 64;
    #pragma unroll
    for (int q = 0; q < 8; ++q) {
        const int cw = 64 * w + 8 * q + (l >> 3);
        const int c4s = (cw >> 2) ^ kk8, c2 = cw & 3;
        const int base = (c4s << 2) + c2 + kk8 * 8 * 256;
        f16x8 o;
        #pragma unroll
        for (int j = 0; j < 8; ++j)
            o[j] = lds[base + j * 256];
        *(f16x8*)&dst[(size_t)cw * 64 + kk8 * 8] = o;
    }
}

// ---------------------------------------------------------------------------
// Gram: GPh[split][sb] = xt(k-half)^T xt(k-half), fp16 MFMA, fp16 output.
// 512 blocks (2/CU), 2-phase pipeline, counted vmcnt(8), setprio on MFMA.
// ---------------------------------------------------------------------------
__global__ __launch_bounds__(256) void gram_kernel(const _Float16* __restrict__ xt,
                                                   _Float16* __restrict__ GPh) {
    const int id = blockIdx.x;                  // 512
    const int vid = (id & 7) * 64 + (id >> 3);  // XCD-contiguous
    const int sb = vid >> 5, rest = vid & 31;
    const int split = rest >> 4, tile = rest & 15;
    const int I0 = (tile >> 2) * 128, J0 = (tile & 3) * 128;
    const _Float16* xb = xt + (size_t)sb * CDIM * NTOK;

    __shared__ _Float16 Ih[2][128 * 64];
    __shared__ _Float16 Jh[2][128 * 64];

    const int t = threadIdx.x, w = t >> 6, l = t & 63;
    const int wm = w >> 1, wn = w & 1, l15 = l & 15, lk = l >> 4;
    const int colr = w * 8 + (l >> 3), pos = l & 7;

    f32x4 acc[4][4];
    #pragma unroll
    for (int f = 0; f < 4; ++f)
        #pragma unroll
        for (int g = 0; g < 4; ++g) acc[f][g] = (f32x4)(0.0f);

    auto STAGE = [&](int bufi, int it) {
        const _Float16* kb = xb + (size_t)(split * 32 + it) * CDIM * 64;
        #pragma unroll
        for (int r = 0; r < 4; ++r) {
            const int colw = r * 32 + colr;
            const int swz = ((pos ^ (colw & 7)) << 3);
            gload_lds16(kb + (size_t)(I0 + colw) * 64 + swz, &Ih[bufi][r * 2048 + w * 512]);
            gload_lds16(kb + (size_t)(J0 + colw) * 64 + swz, &Jh[bufi][r * 2048 + w * 512]);
        }
    };

    STAGE(0, 0);
    for (int it = 0; it < 32; ++it) {
        const int cur = it & 1;
        if (it < 31) {
            STAGE(cur ^ 1, it + 1);
            asm volatile("s_waitcnt vmcnt(8)" ::: "memory");
        } else {
            asm volatile("s_waitcnt vmcnt(0)" ::: "memory");
        }
        __builtin_amdgcn_s_barrier();

        const _Float16* Ib = &Ih[cur][0];
        const _Float16* Jb = &Jh[cur][0];
        __builtin_amdgcn_s_setprio(1);
        #pragma unroll
        for (int ks = 0; ks < 2; ++ks) {
            f16x8 a[4], bb[4];
            #pragma unroll
            for (int f = 0; f < 4; ++f) {
                const int i = wm * 64 + f * 16 + l15;
                a[f] = *(const f16x8*)&Ib[i * 64 + ((ks * 4 + lk) ^ (i & 7)) * 8];
            }
            #pragma unroll
            for (int g = 0; g < 4; ++g) {
                const int j = wn * 64 + g * 16 + l15;
                bb[g] = *(const f16x8*)&Jb[j * 64 + ((ks * 4 + lk) ^ (j & 7)) * 8];
            }
            #pragma unroll
            for (int f = 0; f < 4; ++f)
                #pragma unroll
                for (int g = 0; g < 4; ++g)
                    acc[f][g] = __builtin_amdgcn_mfma_f32_16x16x32_f16(a[f], bb[g], acc[f][g], 0, 0, 0);
        }
        __builtin_amdgcn_s_setprio(0);
        __builtin_amdgcn_s_barrier();
    }

    _Float16* Gout = GPh + ((size_t)split * 16 + sb) * CDIM * CDIM;
    #pragma unroll
    for (int f = 0; f < 4; ++f)
        #pragma unroll
        for (int g = 0; g < 4; ++g) {
            const int row0 = I0 + wm * 64 + f * 16 + lk * 4;
            const int col  = J0 + wn * 64 + g * 16 + l15;
            #pragma unroll
            for (int r = 0; r < 4; ++r)
                Gout[(size_t)(row0 + r) * CDIM + col] = (_Float16)acc[f][g][r];
        }
}

// ---------------------------------------------------------------------------
// T-partials: TP[ks2][sb] = (GPh0+GPh1)(k-range) @ Wv, single fp16 MFMA.
// 512 blocks (2/CU), XCD-aligned with gram's writer (sb in {2g,2g+1} on XCD g)
// so G reads hit the local L2. A: 2x b128 fp16 + packed add. B: gload_lds.
// ---------------------------------------------------------------------------
__global__ __launch_bounds__(256) void t_kernel(const _Float16* __restrict__ GPh,
                                                const _Float16* __restrict__ wvt,
                                                _Float16* __restrict__ TP) {
    const int id = blockIdx.x;                  // 512
    const int vid = (id & 7) * 64 + (id >> 3);  // same XCD map as gram
    const int sb = vid >> 5, rest = vid & 31;
    const int ks2 = rest >> 4, tile = rest & 15;
    const int s = sb >> 3;
    const int I0 = (tile >> 2) * 128, J0 = (tile & 3) * 128;
    const _Float16* G0 = GPh + (size_t)sb * CDIM * CDIM;
    const _Float16* G1 = GPh + ((size_t)16 + sb) * CDIM * CDIM;
    const _Float16* Bv = wvt + (size_t)s * CDIM * CDIM;

    __shared__ _Float16 Ah[128 * 64];
    __shared__ _Float16 Jh[128 * 64];

    const int t = threadIdx.x, w = t >> 6, l = t & 63;
    const int wm = w >> 1, wn = w & 1, l15 = l & 15, lk = l >> 4;
    const int colr = w * 8 + (l >> 3), pos = l & 7;

    f32x4 acc[4][4];
    #pragma unroll
    for (int f = 0; f < 4; ++f)
        #pragma unroll
        for (int g = 0; g < 4; ++g) acc[f][g] = (f32x4)(0.0f);

    for (int it = 0; it < 4; ++it) {
        const int k0 = ks2 * 256 + it * 64;
        __syncthreads();
        // B stage first: async gloads fly while A-stage does its work
        #pragma unroll
        for (int r = 0; r < 4; ++r) {
            const int col = r * 32 + colr;
            const int swz = ((pos ^ (col & 7)) << 3);
            gload_lds16(Bv + (size_t)(J0 + col) * CDIM + k0 + swz, &Jh[r * 2048 + w * 512]);
        }
        // A stage: sum the two fp16 Gram partials, store swizzled
        #pragma unroll
        for (int r = 0; r < 4; ++r) {
            const int i = r * 32 + (t >> 3), ch = t & 7;
            const size_t off = (size_t)(I0 + i) * CDIM + k0 + ch * 8;
            f16x8 a0 = *(const f16x8*)&G0[off];
            f16x8 a1 = *(const f16x8*)&G1[off];
            f16x8 sum = a0 + a1;
            *(f16x8*)&Ah[i * 64 + ((ch ^ (i & 7)) << 3)] = sum;
        }
        __syncthreads();
        __builtin_amdgcn_s_setprio(1);
        #pragma unroll
        for (int ks = 0; ks < 2; ++ks) {
            f16x8 a[4], bb[4];
            #pragma unroll
            for (int f = 0; f < 4; ++f) {
                const int i = wm * 64 + f * 16 + l15;
                a[f] = *(const f16x8*)&Ah[i * 64 + ((ks * 4 + lk) ^ (i & 7)) * 8];
            }
            #pragma unroll
            for (int g = 0; g < 4; ++g) {
                const int j = wn * 64 + g * 16 + l15;
                bb[g] = *(const f16x8*)&Jh[j * 64 + ((ks * 4 + lk) ^ (j & 7)) * 8];
            }
            #pragma unroll
            for (int f = 0; f < 4; ++f)
                #pragma unroll
                for (int g = 0; g < 4; ++g)
                    acc[f][g] = __builtin_amdgcn_mfma_f32_16x16x32_f16(a[f], bb[g], acc[f][g], 0, 0, 0);
        }
        __builtin_amdgcn_s_setprio(0);
    }

    _Float16* Tb = TP + ((size_t)ks2 * 16 + sb) * CDIM * CDIM;
    #pragma unroll
    for (int f = 0; f < 4; ++f)
        #pragma unroll
        for (int g = 0; g < 4; ++g) {
            const int row0 = I0 + wm * 64 + f * 16 + lk * 4;
            const int col  = J0 + wn * 64 + g * 16 + l15;
            #pragma unroll
            for (int r = 0; r < 4; ++r)
                Tb[(size_t)(row0 + r) * CDIM + col] = (_Float16)acc[f][g][r];
        }
}

// ---------------------------------------------------------------------------
// ctx GEMM, K-split by 4: CP[kq][sb][h] = partial Wk_h^T (TP0+TP1)_h
// ---------------------------------------------------------------------------
__global__ __launch_bounds__(256) void ctx_gemm_kernel(const _Float16* __restrict__ TP,
                                                       const float* __restrict__ Wkv1,
                                                       const float* __restrict__ Wkv2,
                                                       float* __restrict__ CP) {
    const int h = blockIdx.x, sb = blockIdx.y, kq = blockIdx.z;
    const int s = sb >> 3;
    const float* W  = (s == 0 ? Wkv1 : Wkv2);
    const _Float16* T0 = TP + (size_t)sb * CDIM * CDIM;
    const _Float16* T1 = TP + ((size_t)16 + sb) * CDIM * CDIM;

    __shared__ float Kt[64][65];
    __shared__ float Tt[64][65];

    const int t = threadIdx.x;
    const int td = t >> 4, te = t & 15;
    float acc[4][4] = {};

    for (int it = 0; it < 2; ++it) {
        const int kc = kq * 128 + it * 64;
        __syncthreads();
        for (int i = 0; i < 16; ++i) {
            const int idx = t + i * 256;
            const int r = idx >> 6, cc = idx & 63;
            Kt[r][cc] = W[(size_t)(kc + r) * (2 * CDIM) + h * HD + cc];
            Tt[r][cc] = (float)T0[(size_t)(kc + r) * CDIM + h * HD + cc]
                      + (float)T1[(size_t)(kc + r) * CDIM + h * HD + cc];
        }
        __syncthreads();
        for (int k = 0; k < 64; ++k) {
            float a[4], bb[4];
            #pragma unroll
            for (int i = 0; i < 4; ++i) a[i] = Kt[k][td * 4 + i];
            #pragma unroll
            for (int j = 0; j < 4; ++j) bb[j] = Tt[k][te * 4 + j];
            #pragma unroll
            for (int i = 0; i < 4; ++i)
                #pragma unroll
                for (int j = 0; j < 4; ++j) acc[i][j] += a[i] * bb[j];
        }
    }
    float* out = CP + (size_t)(((kq * 16 + sb) * HEADS) + h) * HD * HD;
    for (int i = 0; i < 4; ++i)
        for (int j = 0; j < 4; ++j)
            out[(size_t)(td * 4 + i) * HD + te * 4 + j] = acc[i][j];
}

// ---------------------------------------------------------------------------
// ctx finish: sum 4 partials, scale, softmax over d -> smT fp16 [sb][h][e][d]
// ---------------------------------------------------------------------------
__global__ __launch_bounds__(256) void ctx_fin_kernel(const float* __restrict__ CP,
                                                      _Float16* __restrict__ smT) {
    const int h = blockIdx.x, sb = blockIdx.y;

    __shared__ float ctxs[64][65];
    __shared__ float mred[64], sred[64];

    const int t = threadIdx.x;
    const float scale = 0.125f;
    #pragma unroll
    for (int i = 0; i < 4; ++i) {
        const int idx4 = t + i * 256;            // float4 index
        const int d = idx4 >> 4, e4 = idx4 & 15;
        f32x4 sum = (f32x4)(0.0f);
        #pragma unroll
        for (int kq = 0; kq < 4; ++kq) {
            const float* p = CP + (size_t)(((kq * 16 + sb) * HEADS) + h) * HD * HD;
            f32x4 v = *(const f32x4*)&p[d * HD + e4 * 4];
            sum += v;
        }
        *(f32x4*)&ctxs[d][e4 * 4] = sum * scale;
    }
    __syncthreads();
    if (t < 64) {
        float m = -1e30f;
        for (int d = 0; d < 64; ++d) m = fmaxf(m, ctxs[d][t]);
        float ssum = 0.f;
        for (int d = 0; d < 64; ++d) ssum += expf(ctxs[d][t] - m);
        mred[t] = m;
        sred[t] = 1.0f / ssum;
    }
    __syncthreads();
    _Float16* smout = smT + (size_t)(sb * HEADS + h) * HD * HD;   // [e][d]
    #pragma unroll
    for (int i = 0; i < 16; ++i) {
        const int idx = t + i * 256;
        const int e = idx >> 6, d = idx & 63;
        smout[e * HD + d] = (_Float16)(expf(ctxs[d][e] - mred[e]) * sred[e]);
    }
}

// ---------------------------------------------------------------------------
// out: out_s[n, h*64+e] = sum_d x_s[n, h*64+d] * sm[1-s][h][d][e], fp16 MFMA
// ---------------------------------------------------------------------------
__global__ __launch_bounds__(256) void out_kernel(const float* __restrict__ x1,
                                                  const float* __restrict__ x2,
                                                  const _Float16* __restrict__ smT,
                                                  float* __restrict__ out) {
    const int id = blockIdx.x;                   // 4096
    const int vid = (id & 7) * 512 + (id >> 3);  // h-groups co-XCD
    const int h = vid & 7, nt = (vid >> 3) & 31, sb = vid >> 8;
    const int s = sb >> 3, b = sb & 7;
    const float* xs = (s ? x2 : x1) + (size_t)b * NTOK * CDIM;
    const _Float16* sm = smT + (size_t)((((1 - s) * 8 + b) * HEADS) + h) * HD * HD;
    const int n0 = nt * 128;

    __shared__ _Float16 Axt[128 * 64];   // [n][d] swizzled
    __shared__ _Float16 Bsm[64 * 64];    // [e][d] swizzled

    const int t = threadIdx.x, w = t >> 6, l = t & 63;
    const int l15 = l & 15, lk = l >> 4;

    // B stage via gl_lds (2 rounds)
    #pragma unroll
    for (int r = 0; r < 2; ++r) {
        const int e = r * 32 + w * 8 + (l >> 3), pos = l & 7;
        gload_lds16(sm + (size_t)e * HD + ((pos ^ (e & 7)) << 3), &Bsm[r * 2048 + w * 512]);
    }
    // A stage: x f32 -> fp16, swizzled ds_write_b64
    #pragma unroll
    for (int p = 0; p < 8; ++p) {
        const int row = p * 16 + (t >> 4), f4c = t & 15;
        float4 u = *(const float4*)&xs[(size_t)(n0 + row) * CDIM + h * HD + f4c * 4];
        f16x4 q = {(_Float16)u.x, (_Float16)u.y, (_Float16)u.z, (_Float16)u.w};
        const int byte = row * 128 + (((f4c >> 1) ^ (row & 7)) << 4) + ((f4c & 1) << 3);
        *(f16x4*)((char*)Axt + byte) = q;
    }
    __syncthreads();

    f32x4 acc[2][4];
    #pragma unroll
    for (int m = 0; m < 2; ++m)
        #pragma unroll
        for (int g = 0; g < 4; ++g) acc[m][g] = (f32x4)(0.0f);

    #pragma unroll
    for (int ks = 0; ks < 2; ++ks) {
        f16x8 a[2], bb[4];
        #pragma unroll
        for (int m = 0; m < 2; ++m) {
            const int row = w * 32 + m * 16 + l15;
            a[m] = *(const f16x8*)((char*)Axt + row * 128 + (((ks * 4 + lk) ^ (row & 7)) << 4));
        }
        #pragma unroll
        for (int g = 0; g < 4; ++g) {
            const int e = g * 16 + l15;
            bb[g] = *(const f16x8*)((char*)Bsm + e * 128 + (((ks * 4 + lk) ^ (e & 7)) << 4));
        }
        #pragma unroll
        for (int m = 0; m < 2; ++m)
            #pragma unroll
            for (int g = 0; g < 4; ++g)
                acc[m][g] = __builtin_amdgcn_mfma_f32_16x16x32_f16(a[m], bb[g], acc[m][g], 0, 0, 0);
    }

    float* ob = out + (size_t)s * (8ULL * NTOK * CDIM) + (size_t)b * NTOK * CDIM;
    #pragma unroll
    for (int m = 0; m < 2; ++m)
        #pragma unroll
        for (int g = 0; g < 4; ++g) {
            const int row0 = n0 + w * 32 + m * 16 + lk * 4;
            const int col  = h * HD + g * 16 + l15;
            #pragma unroll
            for (int r = 0; r < 4; ++r)
                ob[(size_t)(row0 + r) * CDIM + col] = acc[m][g][r];
        }
}

// ---------------------------------------------------------------------------
extern "C" void kernel_launch(void* const* d_in, const int* in_sizes, int n_in,
                              void* d_out, int out_size, void* d_ws, size_t ws_size,
                              hipStream_t stream) {
    const float* x1   = (const float*)d_in[0];
    const float* x2   = (const float*)d_in[1];
    const float* Wkv1 = (const float*)d_in[2];
    const float* Wkv2 = (const float*)d_in[3];
    float* out = (float*)d_out;

    // Scratch layout inside d_out (128 MiB); every region is dead before
    // out_kernel overwrites d_out. smT (1 MiB) lives in d_ws.
    char* base = (char*)d_out;
    _Float16* XT   = (_Float16*)(base + 0);            // 64 MiB [sb][kb][c][64]
    _Float16* WVT  = (_Float16*)(base + 67108864);     // 1 MiB fp16 [s][j][k]
    _Float16* GPh  = (_Float16*)(base + 68157440);     // 16 MiB fp16 (2 partials)
    _Float16* TP   = (_Float16*)(base + 84934656);     // 16 MiB fp16 (2 partials)
    float*    CP   = (float*)(base + 101711872);       // 8 MiB f32 (4 partials)
    _Float16* SMT  = (_Float16*)d_ws;                  // 1 MiB

    hipLaunchKernelGGL(xpose_kernel, dim3(66, 2, 16), dim3(256), 0, stream,
                       x1, x2, Wkv1, Wkv2, XT, WVT);
    hipLaunchKernelGGL(gram_kernel, dim3(512), dim3(256), 0, stream, XT, GPh);
    hipLaunchKernelGGL(t_kernel, dim3(512), dim3(256), 0, stream, GPh, WVT, TP);
    hipLaunchKernelGGL(ctx_gemm_kernel, dim3(8, 16, 4), dim3(256), 0, stream,
                       TP, Wkv1, Wkv2, CP);
    hipLaunchKernelGGL(ctx_fin_kernel, dim3(8, 16), dim3(256), 0, stream, CP, SMT);
    hipLaunchKernelGGL(out_kernel, dim3(4096), dim3(256), 0, stream, x1, x2, SMT, out);
}